// Round 15
// baseline (142.610 us; speedup 1.0000x reference)
//
#include <hip/hip_runtime.h>

#define HH 2160
#define WW 3840
#define NPATCH 256
#define PSZ 128
#define HW_ (HH*WW)
#define FMSZ (NPATCH*PSZ*PSZ)

#define TW 256
#define TH 8
#define NBX (WW/TW)     // 15
#define NBY (HH/TH)     // 270
#define NB  (NBX*NBY)   // 4050
#define TSTRIDE (NPATCH+1)
#define NRECC (NB*8)    // wave records per channel = 32400
#define FIN_BLKS 192    // finalize1 grid (64,3)

typedef float fx4 __attribute__((ext_vector_type(4)));
typedef float fx4u __attribute__((ext_vector_type(4), aligned(4)));
typedef unsigned char uchar;

// ws layout: fm | tot(13 dbl) | done ctr | coef | partial(3*NRECC*8 f32) | hbb | tlist
#define TOT_OFF   ((size_t)FMSZ*4)
#define DONE_OFF  (TOT_OFF + 104)
#define COEF_OFF  (TOT_OFF + 128)
#define PART_OFF  (TOT_OFF + 192)
#define HBB_OFF   ((PART_OFF + (size_t)3*NRECC*8*4 + 63)/64*64)
#define TLIST_OFF ((HBB_OFF + (size_t)(HW_/4) + 63)/64*64)
#define WS_NEED   (TLIST_OFF + (size_t)NB*TSTRIDE*4)

// barrier that does NOT drain vmcnt (fallback path only)
#define BARLDS() do { \
    asm volatile("s_waitcnt lgkmcnt(0)" ::: "memory"); \
    __builtin_amdgcn_s_barrier(); \
    asm volatile("" ::: "memory"); \
} while (0)

// ---------------- fused: hole-byte map + per-tile ordered patch list + tot/ctr zero ----------------
__global__ __launch_bounds__(256) void hbbtl_kernel(
        const float* __restrict__ mask, const int* __restrict__ pos_y,
        const int* __restrict__ pos_x, uchar* __restrict__ hbb,
        unsigned int* __restrict__ tlist, double* __restrict__ tot,
        unsigned int* __restrict__ done) {
    __shared__ unsigned long long wm[4];
    const int tile = blockIdx.x;
    const int tx0 = (tile % NBX) * TW;
    const int ty0 = (tile / NBX) * TH;
    const int tid = threadIdx.x;
    const int lane = tid & 63;
    const int wid  = tid >> 6;

    if (tile == 0) {
        if (tid < 13) tot[tid] = 0.0;
        if (tid == 13) *done = 0u;
    }

    // hbb for this tile's 512 quads (2 per thread)
    #pragma unroll
    for (int h = 0; h < 2; ++h) {
        const int l = tid + h*256;
        const int row = l >> 6, col = l & 63;
        const int q = (ty0+row)*(WW >> 2) + (tx0 >> 2) + col;
        const fx4 m = ((const fx4*)mask)[q];
        hbb[q] = (uchar)((unsigned)(m.x!=0.f) | ((unsigned)(m.y!=0.f)<<1)
                       | ((unsigned)(m.z!=0.f)<<2) | ((unsigned)(m.w!=0.f)<<3));
    }

    // ordered (ascending n) patch list for this tile
    const int yn = pos_y[tid], xn = pos_x[tid];
    const bool cov = (yn < ty0 + TH) && (yn + PSZ > ty0) &&
                     (xn < tx0 + TW) && (xn + PSZ > tx0);
    unsigned long long b = __ballot(cov);
    if (lane == 0) wm[wid] = b;
    __syncthreads();
    unsigned int* tl = tlist + (size_t)tile * TSTRIDE;
    if (cov) {
        int pos = __popcll(b & ((1ull << lane) - 1ull));
        for (int w = 0; w < wid; ++w) pos += __popcll(wm[w]);
        tl[1 + pos] = ((unsigned)tid << 24) | ((unsigned)yn << 12) | (unsigned)xn;
    }
    if (tid == 0)
        tl[0] = (unsigned)(__popcll(wm[0]) + __popcll(wm[1]) + __popcll(wm[2]) + __popcll(wm[3]));
}

// ---------------- feather: separable 9-tap gaussian, zero-padded per patch ----------------
__global__ __launch_bounds__(256) void feather_kernel(
        const float* __restrict__ mask, const uchar* __restrict__ hbb,
        const int* __restrict__ pos_y, const int* __restrict__ pos_x,
        float* __restrict__ fm) {
    __shared__ float sm[40*PSZ];
    __shared__ float tp[40*PSZ];
    const int n = blockIdx.x;
    const int r0 = blockIdx.y * 32;
    const int y0 = pos_y[n], x0 = pos_x[n];
    float g[9]; float s = 0.f;
    #pragma unroll
    for (int k = 0; k < 9; ++k) { float xx = (k-4)*0.75f; g[k] = expf(-0.5f*xx*xx); s += g[k]; }
    const float inv = 1.f/s;
    #pragma unroll
    for (int k = 0; k < 9; ++k) g[k] *= inv;

    for (int idx = threadIdx.x; idx < 40*PSZ; idx += 256) {
        int l = idx >> 7, j = idx & 127;
        int r = r0 + l - 4;
        float mv = 0.f;
        if ((unsigned)r < (unsigned)PSZ) {
            const int pix = (y0+r)*WW + (x0+j);
            if (hbb) mv = (float)((hbb[pix >> 2] >> (pix & 3)) & 1u);
            else     mv = mask[pix];
        }
        sm[idx] = mv;
    }
    __syncthreads();
    for (int idx = threadIdx.x; idx < 40*PSZ; idx += 256) {
        int l = idx >> 7, j = idx & 127;
        float a = 0.f;
        #pragma unroll
        for (int d = -4; d <= 4; ++d) {
            int jj = j + d;
            if (jj >= 0 && jj < PSZ) a += sm[(l<<7)+jj]*g[d+4];
        }
        tp[idx] = a;
    }
    __syncthreads();
    float* o = fm + n*(PSZ*PSZ) + r0*PSZ;
    for (int idx = threadIdx.x; idx < 32*PSZ; idx += 256) {
        int i = idx >> 7, j = idx & 127;
        float a = 0.f;
        #pragma unroll
        for (int d = 0; d < 9; ++d) a += tp[((i+d)<<7)+j]*g[d];
        o[idx] = a;
    }
}

// ---------------- compose: tlist-driven, NO barriers / NO LDS; cacheable orig load ----------------
__global__ __launch_bounds__(512) void compose_kernel(
        const float* __restrict__ orig, const float* __restrict__ patches,
        const float* __restrict__ fm, float* __restrict__ out,
        float* __restrict__ partial, const uchar* __restrict__ hbb,
        const unsigned int* __restrict__ tlist) {
    const int tid = threadIdx.x;
    const int lane = tid & 63;
    const int wid  = tid >> 6;              // 0..7 = row within tile
    const int tx0 = blockIdx.x * TW;
    const int ty0 = blockIdx.y * TH;
    const int chan = blockIdx.z;

    const int x0 = tx0 + lane * 4;          // this thread's pixel quad
    const int y  = ty0 + wid;               // this thread's row
    const int q = (y*WW + x0) >> 2;
    const int pq = chan*(HW_ >> 2) + q;

    const fx4* __restrict__ orig4 = (const fx4*)orig;
    fx4* __restrict__ out4 = (fx4*)out;

    // per-thread vector loads issue immediately (plain load: allow L2/L3 retention)
    const uchar hbv = hbb[q];
    fx4 v = orig4[pq];

    // block-uniform tile list -> scalar loads
    const unsigned int* __restrict__ tl =
        tlist + (size_t)(blockIdx.y * NBX + blockIdx.x) * TSTRIDE;
    const int cnt = (int)tl[0];

    const float nhx = (hbv & 1u) ? 0.f : 1.f;
    const float nhy = (hbv & 2u) ? 0.f : 1.f;
    const float nhz = (hbv & 4u) ? 0.f : 1.f;
    const float nhw = (hbv & 8u) ? 0.f : 1.f;

    const float a_cnt = nhx+nhy+nhz+nhw;
    const float s1o = v.x*nhx+v.y*nhy+v.z*nhz+v.w*nhw;
    const float s2o = v.x*v.x*nhx+v.y*v.y*nhy+v.z*v.z*nhz+v.w*v.w*nhw;

    for (int k = 0; k < cnt; ++k) {
        const unsigned e = tl[1 + k];
        const int xk = (int)(e & 0xFFFu);
        const int yk = (int)((e >> 12) & 0xFFFu);
        const int nn = (int)(e >> 24);
        const int dy = y - yk;
        if ((unsigned)dy >= (unsigned)PSZ) continue;
        const int dx0 = x0 - xk;
        if (dx0 <= -4 || dx0 >= PSZ) continue;
        const int rowb = dy << 7;
        const float* __restrict__ fmp = fm + nn*(PSZ*PSZ) + rowb;
        const float* __restrict__ pp  = patches + (nn*3 + chan)*(PSZ*PSZ) + rowb;
        if ((unsigned)dx0 <= (unsigned)(PSZ-4)) {
            const fx4u f4 = *(const fx4u*)(fmp + dx0);
            const fx4u p4 = *(const fx4u*)(pp + dx0);
            v.x += f4.x * (p4.x - v.x);
            v.y += f4.y * (p4.y - v.y);
            v.z += f4.z * (p4.z - v.z);
            v.w += f4.w * (p4.w - v.w);
        } else {
            #define BLEND(J, MX) { \
                const int dx = dx0 + J; \
                if ((unsigned)dx < (unsigned)PSZ) { \
                    const float f = fmp[dx]; \
                    v.MX += f * (pp[dx] - v.MX); \
                } }
            BLEND(0, x) BLEND(1, y) BLEND(2, z) BLEND(3, w)
            #undef BLEND
        }
    }

    out4[pq] = v;

    const float s1f = v.x*nhx+v.y*nhy+v.z*nhz+v.w*nhw;
    const float s2f = v.x*v.x*nhx+v.y*v.y*nhy+v.z*v.z*nhz+v.w*v.w*nhw;

    // --- tail: per-wave shuffle reduce; lane 0 writes one 32 B record. No barrier. ---
    float vals[5] = {s1o, s2o, s1f, s2f, a_cnt};
    #pragma unroll
    for (int i = 0; i < 5; ++i) {
        float t = vals[i];
        t += __shfl_down(t, 32); t += __shfl_down(t, 16);
        t += __shfl_down(t, 8);  t += __shfl_down(t, 4);
        t += __shfl_down(t, 2);  t += __shfl_down(t, 1);
        vals[i] = t;
    }
    if (lane == 0) {
        const int gw = (((chan*NBY + blockIdx.y)*NBX + blockIdx.x) << 3) + wid;
        float* rec = partial + (size_t)gw*8;
        fx4 r4 = {vals[0], vals[1], vals[2], vals[3]};
        *(fx4*)rec = r4;
        rec[4] = vals[4];
    }
}

// ---------------- finalize1: grid (64,3); record reduce -> atomics; last block emits coef ----------------
__global__ __launch_bounds__(256) void finalize1_kernel(
        const float* __restrict__ partial, double* __restrict__ tot,
        unsigned int* __restrict__ done, float* __restrict__ coef) {
    __shared__ double red[4][5];
    __shared__ bool last;
    const int chan = blockIdx.y;
    const int tid = threadIdx.x;
    const int lane = tid & 63;
    const int w = tid >> 6;
    const float* __restrict__ base = partial + (size_t)chan*NRECC*8;
    double a0=0, a1=0, a2=0, a3=0, a4=0;
    for (int r = blockIdx.x*256 + tid; r < NRECC; r += 64*256) {
        const float* rec = base + (size_t)r*8;
        const fx4 p = *(const fx4*)rec;
        a0 += (double)p.x; a1 += (double)p.y; a2 += (double)p.z; a3 += (double)p.w;
        a4 += (double)rec[4];
    }
    double vals[5] = {a0, a1, a2, a3, a4};
    #pragma unroll
    for (int i = 0; i < 5; ++i) {
        double t = vals[i];
        t += __shfl_down(t, 32); t += __shfl_down(t, 16);
        t += __shfl_down(t, 8);  t += __shfl_down(t, 4);
        t += __shfl_down(t, 2);  t += __shfl_down(t, 1);
        vals[i] = t;
    }
    if (lane == 0) {
        #pragma unroll
        for (int i = 0; i < 5; ++i) red[w][i] = vals[i];
    }
    __syncthreads();
    if (tid == 0) {
        double s0 = red[0][0]+red[1][0]+red[2][0]+red[3][0];
        double s1 = red[0][1]+red[1][1]+red[2][1]+red[3][1];
        double s2 = red[0][2]+red[1][2]+red[2][2]+red[3][2];
        double s3 = red[0][3]+red[1][3]+red[2][3]+red[3][3];
        double s4 = red[0][4]+red[1][4]+red[2][4]+red[3][4];
        atomicAdd(&tot[1+chan],  s0);
        atomicAdd(&tot[4+chan],  s1);
        atomicAdd(&tot[7+chan],  s2);
        atomicAdd(&tot[10+chan], s3);
        atomicAdd(&tot[0],       s4);   // summed over 3 channels -> /3 below
        __threadfence();
        last = (atomicAdd(done, 1u) == FIN_BLKS - 1u);
    }
    __syncthreads();
    if (last && tid == 0) {
        const double cnt = tot[0] / 3.0;
        for (int c = 0; c < 3; ++c) {
            double om = tot[1+c]/cnt;
            double ov = tot[4+c]/cnt - om*om;
            double os = sqrt(ov > 0.0 ? ov : 0.0);
            double fmn = tot[7+c]/cnt;
            double fv = tot[10+c]/cnt - fmn*fmn;
            double fs = sqrt(fv > 0.0 ? fv : 0.0);
            coef[c]   = (float)(os/(fs + 1e-8));
            coef[3+c] = (float)fmn;
            coef[6+c] = (float)om;
        }
    }
}

// ---------------- correct: hb-byte driven, one quad per thread ----------------
__global__ __launch_bounds__(256) void correct_kernel(
        float* __restrict__ out, const uchar* __restrict__ hbb,
        const float* __restrict__ coef) {
    const int q = blockIdx.x * 256 + threadIdx.x;
    if (q >= (HW_ >> 2)) return;
    const unsigned bits = hbb[q];
    if (!bits) return;
    const float r0 = coef[0], r1 = coef[1], r2 = coef[2];
    const float f0 = coef[3], f1 = coef[4], f2 = coef[5];
    const float o0 = coef[6], o1 = coef[7], o2 = coef[8];
    fx4* __restrict__ out4 = (fx4*)out;
    fx4 v0 = out4[q];
    fx4 v1 = out4[(HW_>>2)+q];
    fx4 v2 = out4[((2*HW_)>>2)+q];
    if (bits & 1u) { v0.x=(v0.x-f0)*r0+o0; v1.x=(v1.x-f1)*r1+o1; v2.x=(v2.x-f2)*r2+o2; }
    if (bits & 2u) { v0.y=(v0.y-f0)*r0+o0; v1.y=(v1.y-f1)*r1+o1; v2.y=(v2.y-f2)*r2+o2; }
    if (bits & 4u) { v0.z=(v0.z-f0)*r0+o0; v1.z=(v1.z-f1)*r1+o1; v2.z=(v2.z-f2)*r2+o2; }
    if (bits & 8u) { v0.w=(v0.w-f0)*r0+o0; v1.w=(v1.w-f1)*r1+o1; v2.w=(v2.w-f2)*r2+o2; }
    out4[q] = v0;
    out4[(HW_>>2)+q] = v1;
    out4[((2*HW_)>>2)+q] = v2;
}

// ================= fallback path (ws too small): R10-style =================
__global__ __launch_bounds__(512) void compose_fb_kernel(
        const float* __restrict__ orig, const float* __restrict__ patches,
        const float* __restrict__ mask, const int* __restrict__ pos_y,
        const int* __restrict__ pos_x, const float* __restrict__ fm,
        float* __restrict__ out, float* __restrict__ partial) {
    __shared__ int ln[NPATCH];
    __shared__ int ly[NPATCH];
    __shared__ int lx[NPATCH];
    __shared__ unsigned long long wm[4];
    __shared__ float sv[5][520];

    const int tid = threadIdx.x;
    const int lane = tid & 63;
    const int wid  = tid >> 6;
    const int tx0 = blockIdx.x * TW;
    const int ty0 = blockIdx.y * TH;
    const int chan = blockIdx.z;

    const int x0 = tx0 + lane * 4;
    const int y  = ty0 + wid;
    const int q = (y*WW + x0) >> 2;
    const int pq = chan*(HW_ >> 2) + q;

    const fx4* __restrict__ orig4 = (const fx4*)orig;
    fx4* __restrict__ out4 = (fx4*)out;

    const fx4 mq = ((const fx4*)mask)[q];
    fx4 v = orig4[pq];

    if (tid < NPATCH) {
        const int yn = pos_y[tid], xn = pos_x[tid];
        const bool cov = (yn < ty0 + TH) && (yn + PSZ > ty0) &&
                         (xn < tx0 + TW) && (xn + PSZ > tx0);
        unsigned long long b = __ballot(cov);
        if (lane == 0) wm[wid] = b;
        BARLDS();
        if (cov) {
            int pos = __popcll(b & ((1ull << lane) - 1ull));
            for (int w = 0; w < wid; ++w) pos += __popcll(wm[w]);
            ln[pos] = tid; ly[pos] = yn; lx[pos] = xn;
        }
    } else {
        BARLDS();
    }
    BARLDS();
    const int cnt = __popcll(wm[0]) + __popcll(wm[1]) + __popcll(wm[2]) + __popcll(wm[3]);

    const float nhx = 1.f-mq.x, nhy = 1.f-mq.y, nhz = 1.f-mq.z, nhw = 1.f-mq.w;
    const float a_cnt = nhx+nhy+nhz+nhw;
    const float s1o = v.x*nhx+v.y*nhy+v.z*nhz+v.w*nhw;
    const float s2o = v.x*v.x*nhx+v.y*v.y*nhy+v.z*v.z*nhz+v.w*v.w*nhw;

    for (int k = 0; k < cnt; ++k) {
        const int dy = y - ly[k];
        if ((unsigned)dy >= (unsigned)PSZ) continue;
        const int dx0 = x0 - lx[k];
        if (dx0 <= -4 || dx0 >= PSZ) continue;
        const int nn = ln[k];
        const int rowb = dy << 7;
        const float* __restrict__ fmp = fm + nn*(PSZ*PSZ) + rowb;
        const float* __restrict__ pp  = patches + (nn*3 + chan)*(PSZ*PSZ) + rowb;
        if ((unsigned)dx0 <= (unsigned)(PSZ-4)) {
            const fx4u f4 = *(const fx4u*)(fmp + dx0);
            const fx4u p4 = *(const fx4u*)(pp + dx0);
            v.x += f4.x * (p4.x - v.x);
            v.y += f4.y * (p4.y - v.y);
            v.z += f4.z * (p4.z - v.z);
            v.w += f4.w * (p4.w - v.w);
        } else {
            #define BLEND(J, MX) { \
                const int dx = dx0 + J; \
                if ((unsigned)dx < (unsigned)PSZ) { \
                    const float f = fmp[dx]; \
                    v.MX += f * (pp[dx] - v.MX); \
                } }
            BLEND(0, x) BLEND(1, y) BLEND(2, z) BLEND(3, w)
            #undef BLEND
        }
    }

    out4[pq] = v;

    const float s1f = v.x*nhx+v.y*nhy+v.z*nhz+v.w*nhw;
    const float s2f = v.x*v.x*nhx+v.y*v.y*nhy+v.z*v.z*nhz+v.w*v.w*nhw;

    sv[0][tid] = s1o; sv[1][tid] = s2o; sv[2][tid] = s1f; sv[3][tid] = s2f; sv[4][tid] = a_cnt;
    BARLDS();
    if (wid < 5 && !(wid == 4 && chan != 0)) {
        const float* p = sv[wid];
        float t = p[lane] + p[lane+64] + p[lane+128] + p[lane+192]
                + p[lane+256] + p[lane+320] + p[lane+384] + p[lane+448];
        t += __shfl_down(t, 32); t += __shfl_down(t, 16);
        t += __shfl_down(t, 8);  t += __shfl_down(t, 4);
        t += __shfl_down(t, 2);  t += __shfl_down(t, 1);
        if (lane == 0) {
            const int bid = blockIdx.y * NBX + blockIdx.x;
            const int stat = (wid == 4) ? 0 : (1 + 3*wid + chan);
            partial[stat*NB + bid] = t;
        }
    }
}

__global__ __launch_bounds__(832) void finalize_fb_kernel(
        const float* __restrict__ partial, float* __restrict__ coef) {
    __shared__ double tot[13];
    const int w = threadIdx.x >> 6;
    const int lane = threadIdx.x & 63;
    const float* p = partial + w*NB;
    double s0 = 0.0, s1 = 0.0;
    int b = lane;
    for (; b + 64 < NB; b += 128) { s0 += (double)p[b]; s1 += (double)p[b+64]; }
    if (b < NB) s0 += (double)p[b];
    double t = s0 + s1;
    t += __shfl_down(t, 32); t += __shfl_down(t, 16);
    t += __shfl_down(t, 8);  t += __shfl_down(t, 4);
    t += __shfl_down(t, 2);  t += __shfl_down(t, 1);
    if (lane == 0) tot[w] = t;
    __syncthreads();
    if (threadIdx.x == 0) {
        const double cnt = tot[0];
        for (int c = 0; c < 3; ++c) {
            double om = tot[1+c]/cnt;
            double ov = tot[4+c]/cnt - om*om;
            double os = sqrt(ov > 0.0 ? ov : 0.0);
            double fmn = tot[7+c]/cnt;
            double fv = tot[10+c]/cnt - fmn*fmn;
            double fs = sqrt(fv > 0.0 ? fv : 0.0);
            coef[c]   = (float)(os/(fs + 1e-8));
            coef[3+c] = (float)fmn;
            coef[6+c] = (float)om;
        }
    }
}

__global__ __launch_bounds__(256) void correct_full_kernel(
        float* __restrict__ out, const float* __restrict__ mask,
        const float* __restrict__ coef) {
    const int q = blockIdx.x * 256 + threadIdx.x;
    if (q >= (HW_ >> 2)) return;
    const fx4 m = ((const fx4*)mask)[q];
    if (m.x == 0.f && m.y == 0.f && m.z == 0.f && m.w == 0.f) return;
    const float r0 = coef[0], r1 = coef[1], r2 = coef[2];
    const float f0 = coef[3], f1 = coef[4], f2 = coef[5];
    const float o0 = coef[6], o1 = coef[7], o2 = coef[8];
    fx4* __restrict__ out4 = (fx4*)out;
    fx4 v0 = out4[q];
    fx4 v1 = out4[(HW_>>2)+q];
    fx4 v2 = out4[((2*HW_)>>2)+q];
    if (m.x != 0.f) { v0.x=(v0.x-f0)*r0+o0; v1.x=(v1.x-f1)*r1+o1; v2.x=(v2.x-f2)*r2+o2; }
    if (m.y != 0.f) { v0.y=(v0.y-f0)*r0+o0; v1.y=(v1.y-f1)*r1+o1; v2.y=(v2.y-f2)*r2+o2; }
    if (m.z != 0.f) { v0.z=(v0.z-f0)*r0+o0; v1.z=(v1.z-f1)*r1+o1; v2.z=(v2.z-f2)*r2+o2; }
    if (m.w != 0.f) { v0.w=(v0.w-f0)*r0+o0; v1.w=(v1.w-f1)*r1+o1; v2.w=(v2.w-f2)*r2+o2; }
    out4[q] = v0;
    out4[(HW_>>2)+q] = v1;
    out4[((2*HW_)>>2)+q] = v2;
}

extern "C" void kernel_launch(void* const* d_in, const int* in_sizes, int n_in,
                              void* d_out, int out_size, void* d_ws, size_t ws_size,
                              hipStream_t stream) {
    const float* orig    = (const float*)d_in[0];
    const float* patches = (const float*)d_in[1];
    const float* mask    = (const float*)d_in[2];
    const int*   pos_y   = (const int*)d_in[3];
    const int*   pos_x   = (const int*)d_in[4];
    float* out = (float*)d_out;

    float*        fm      = (float*)d_ws;
    double*       tot     = (double*)((char*)d_ws + TOT_OFF);
    unsigned int* done    = (unsigned int*)((char*)d_ws + DONE_OFF);
    float*        coef    = (float*)((char*)d_ws + COEF_OFF);
    float*        partial = (float*)((char*)d_ws + PART_OFF);
    uchar*        hbb     = (uchar*)((char*)d_ws + HBB_OFF);
    unsigned int* tlist   = (unsigned int*)((char*)d_ws + TLIST_OFF);

    const bool fast = (ws_size >= WS_NEED);

    dim3 fg(NPATCH, 4);
    dim3 g(NBX, NBY, 3);
    if (fast) {
        hbbtl_kernel<<<NB, 256, 0, stream>>>(mask, pos_y, pos_x, hbb, tlist, tot, done);
        feather_kernel<<<fg, 256, 0, stream>>>(mask, hbb, pos_y, pos_x, fm);
        compose_kernel<<<g, 512, 0, stream>>>(orig, patches, fm, out, partial, hbb, tlist);
        dim3 fz(64, 3);
        finalize1_kernel<<<fz, 256, 0, stream>>>(partial, tot, done, coef);
        correct_kernel<<<((HW_ >> 2) + 255)/256, 256, 0, stream>>>(out, hbb, coef);
    } else {
        feather_kernel<<<fg, 256, 0, stream>>>(mask, nullptr, pos_y, pos_x, fm);
        compose_fb_kernel<<<g, 512, 0, stream>>>(orig, patches, mask, pos_y, pos_x, fm,
                                                 out, partial);
        finalize_fb_kernel<<<1, 832, 0, stream>>>(partial, coef);
        correct_full_kernel<<<((HW_ >> 2) + 255)/256, 256, 0, stream>>>(out, mask, coef);
    }
}

// Round 16
// 125.639 us; speedup vs baseline: 1.1351x; 1.1351x over previous
//
#include <hip/hip_runtime.h>

#define HH 2160
#define WW 3840
#define NPATCH 256
#define PSZ 128
#define HW_ (HH*WW)
#define FMSZ (NPATCH*PSZ*PSZ)

#define TW 256
#define TH 8
#define NBX (WW/TW)     // 15
#define NBY (HH/TH)     // 270
#define NB  (NBX*NBY)   // 4050
#define TSTRIDE (NPATCH+1)

typedef float fx4 __attribute__((ext_vector_type(4)));
typedef float fx4u __attribute__((ext_vector_type(4), aligned(4)));
typedef unsigned char uchar;

// ws layout: fm | coef | partial[13][NB] | hbb | tlist
#define COEF_OFF  ((size_t)FMSZ*4)
#define PART_OFF  (COEF_OFF + 64)
#define HBB_OFF   ((PART_OFF + (size_t)13*NB*4 + 63)/64*64)
#define TLIST_OFF ((HBB_OFF + (size_t)(HW_/4) + 63)/64*64)
#define WS_NEED   (TLIST_OFF + (size_t)NB*TSTRIDE*4)

// barrier that does NOT drain vmcnt
#define BARLDS() do { \
    asm volatile("s_waitcnt lgkmcnt(0)" ::: "memory"); \
    __builtin_amdgcn_s_barrier(); \
    asm volatile("" ::: "memory"); \
} while (0)

// ---------------- fused: hole-byte map for own tile + per-tile ordered patch list ----------------
__global__ __launch_bounds__(256) void hbbtl_kernel(
        const float* __restrict__ mask, const int* __restrict__ pos_y,
        const int* __restrict__ pos_x, uchar* __restrict__ hbb,
        unsigned int* __restrict__ tlist) {
    __shared__ unsigned long long wm[4];
    const int tile = blockIdx.x;
    const int tx0 = (tile % NBX) * TW;
    const int ty0 = (tile / NBX) * TH;
    const int tid = threadIdx.x;
    const int lane = tid & 63;
    const int wid  = tid >> 6;

    // hbb for this tile's 512 quads (2 per thread)
    #pragma unroll
    for (int h = 0; h < 2; ++h) {
        const int l = tid + h*256;
        const int row = l >> 6, col = l & 63;
        const int q = (ty0+row)*(WW >> 2) + (tx0 >> 2) + col;
        const fx4 m = ((const fx4*)mask)[q];
        hbb[q] = (uchar)((unsigned)(m.x!=0.f) | ((unsigned)(m.y!=0.f)<<1)
                       | ((unsigned)(m.z!=0.f)<<2) | ((unsigned)(m.w!=0.f)<<3));
    }

    // ordered (ascending n) patch list for this tile
    const int yn = pos_y[tid], xn = pos_x[tid];
    const bool cov = (yn < ty0 + TH) && (yn + PSZ > ty0) &&
                     (xn < tx0 + TW) && (xn + PSZ > tx0);
    unsigned long long b = __ballot(cov);
    if (lane == 0) wm[wid] = b;
    __syncthreads();
    unsigned int* tl = tlist + (size_t)tile * TSTRIDE;
    if (cov) {
        int pos = __popcll(b & ((1ull << lane) - 1ull));
        for (int w = 0; w < wid; ++w) pos += __popcll(wm[w]);
        tl[1 + pos] = ((unsigned)tid << 24) | ((unsigned)yn << 12) | (unsigned)xn;
    }
    if (tid == 0)
        tl[0] = (unsigned)(__popcll(wm[0]) + __popcll(wm[1]) + __popcll(wm[2]) + __popcll(wm[3]));
}

// ---------------- feather: separable 9-tap gaussian, zero-padded per patch ----------------
__global__ __launch_bounds__(256) void feather_kernel(
        const float* __restrict__ mask, const uchar* __restrict__ hbb,
        const int* __restrict__ pos_y, const int* __restrict__ pos_x,
        float* __restrict__ fm) {
    __shared__ float sm[40*PSZ];
    __shared__ float tp[40*PSZ];
    const int n = blockIdx.x;
    const int r0 = blockIdx.y * 32;
    const int y0 = pos_y[n], x0 = pos_x[n];
    float g[9]; float s = 0.f;
    #pragma unroll
    for (int k = 0; k < 9; ++k) { float xx = (k-4)*0.75f; g[k] = expf(-0.5f*xx*xx); s += g[k]; }
    const float inv = 1.f/s;
    #pragma unroll
    for (int k = 0; k < 9; ++k) g[k] *= inv;

    for (int idx = threadIdx.x; idx < 40*PSZ; idx += 256) {
        int l = idx >> 7, j = idx & 127;
        int r = r0 + l - 4;
        float mv = 0.f;
        if ((unsigned)r < (unsigned)PSZ) {
            const int pix = (y0+r)*WW + (x0+j);
            if (hbb) mv = (float)((hbb[pix >> 2] >> (pix & 3)) & 1u);
            else     mv = mask[pix];
        }
        sm[idx] = mv;
    }
    __syncthreads();
    for (int idx = threadIdx.x; idx < 40*PSZ; idx += 256) {
        int l = idx >> 7, j = idx & 127;
        float a = 0.f;
        #pragma unroll
        for (int d = -4; d <= 4; ++d) {
            int jj = j + d;
            if (jj >= 0 && jj < PSZ) a += sm[(l<<7)+jj]*g[d+4];
        }
        tp[idx] = a;
    }
    __syncthreads();
    float* o = fm + n*(PSZ*PSZ) + r0*PSZ;
    for (int idx = threadIdx.x; idx < 32*PSZ; idx += 256) {
        int i = idx >> 7, j = idx & 127;
        float a = 0.f;
        #pragma unroll
        for (int d = 0; d < 9; ++d) a += tp[((i+d)<<7)+j]*g[d];
        o[idx] = a;
    }
}

// ---------------- compose (primary): tlist-driven, no startup barriers ----------------
__global__ __launch_bounds__(512) void compose_kernel(
        const float* __restrict__ orig, const float* __restrict__ patches,
        const float* __restrict__ fm, float* __restrict__ out,
        float* __restrict__ partial, const uchar* __restrict__ hbb,
        const unsigned int* __restrict__ tlist) {
    __shared__ float sv[5][520];

    const int tid = threadIdx.x;
    const int lane = tid & 63;
    const int wid  = tid >> 6;              // 0..7 = row within tile
    const int tx0 = blockIdx.x * TW;
    const int ty0 = blockIdx.y * TH;
    const int chan = blockIdx.z;

    const int x0 = tx0 + lane * 4;          // this thread's pixel quad
    const int y  = ty0 + wid;               // this thread's row
    const int q = (y*WW + x0) >> 2;
    const int pq = chan*(HW_ >> 2) + q;

    const fx4* __restrict__ orig4 = (const fx4*)orig;
    fx4* __restrict__ out4 = (fx4*)out;

    // per-thread vector loads issue immediately
    const uchar hbv = hbb[q];
    fx4 v = __builtin_nontemporal_load(&orig4[pq]);

    // block-uniform tile list -> scalar loads
    const unsigned int* __restrict__ tl =
        tlist + (size_t)(blockIdx.y * NBX + blockIdx.x) * TSTRIDE;
    const int cnt = (int)tl[0];

    const float nhx = (hbv & 1u) ? 0.f : 1.f;
    const float nhy = (hbv & 2u) ? 0.f : 1.f;
    const float nhz = (hbv & 4u) ? 0.f : 1.f;
    const float nhw = (hbv & 8u) ? 0.f : 1.f;

    const float a_cnt = nhx+nhy+nhz+nhw;
    const float s1o = v.x*nhx+v.y*nhy+v.z*nhz+v.w*nhw;
    const float s2o = v.x*v.x*nhx+v.y*v.y*nhy+v.z*v.z*nhz+v.w*v.w*nhw;

    for (int k = 0; k < cnt; ++k) {
        const unsigned e = tl[1 + k];
        const int xk = (int)(e & 0xFFFu);
        const int yk = (int)((e >> 12) & 0xFFFu);
        const int nn = (int)(e >> 24);
        const int dy = y - yk;
        if ((unsigned)dy >= (unsigned)PSZ) continue;
        const int dx0 = x0 - xk;
        if (dx0 <= -4 || dx0 >= PSZ) continue;
        const int rowb = dy << 7;
        const float* __restrict__ fmp = fm + nn*(PSZ*PSZ) + rowb;
        const float* __restrict__ pp  = patches + (nn*3 + chan)*(PSZ*PSZ) + rowb;
        if ((unsigned)dx0 <= (unsigned)(PSZ-4)) {
            const fx4u f4 = *(const fx4u*)(fmp + dx0);
            const fx4u p4 = *(const fx4u*)(pp + dx0);
            v.x += f4.x * (p4.x - v.x);
            v.y += f4.y * (p4.y - v.y);
            v.z += f4.z * (p4.z - v.z);
            v.w += f4.w * (p4.w - v.w);
        } else {
            #define BLEND(J, MX) { \
                const int dx = dx0 + J; \
                if ((unsigned)dx < (unsigned)PSZ) { \
                    const float f = fmp[dx]; \
                    v.MX += f * (pp[dx] - v.MX); \
                } }
            BLEND(0, x) BLEND(1, y) BLEND(2, z) BLEND(3, w)
            #undef BLEND
        }
    }

    out4[pq] = v;

    const float s1f = v.x*nhx+v.y*nhy+v.z*nhz+v.w*nhw;
    const float s2f = v.x*v.x*nhx+v.y*v.y*nhy+v.z*v.z*nhz+v.w*v.w*nhw;

    // --- tail: LDS transpose, 5 waves reduce 512 values each ---
    sv[0][tid] = s1o; sv[1][tid] = s2o; sv[2][tid] = s1f; sv[3][tid] = s2f; sv[4][tid] = a_cnt;
    BARLDS();
    if (wid < 5 && !(wid == 4 && chan != 0)) {
        const float* p = sv[wid];
        float t = p[lane] + p[lane+64] + p[lane+128] + p[lane+192]
                + p[lane+256] + p[lane+320] + p[lane+384] + p[lane+448];
        t += __shfl_down(t, 32); t += __shfl_down(t, 16);
        t += __shfl_down(t, 8);  t += __shfl_down(t, 4);
        t += __shfl_down(t, 2);  t += __shfl_down(t, 1);
        if (lane == 0) {
            const int bid = blockIdx.y * NBX + blockIdx.x;
            const int stat = (wid == 4) ? 0 : (1 + 3*wid + chan);
            partial[stat*NB + bid] = t;
        }
    }
}

// ---------------- compose fallback (ws too small): in-block ballot, mask-based ----------------
__global__ __launch_bounds__(512) void compose_fb_kernel(
        const float* __restrict__ orig, const float* __restrict__ patches,
        const float* __restrict__ mask, const int* __restrict__ pos_y,
        const int* __restrict__ pos_x, const float* __restrict__ fm,
        float* __restrict__ out, float* __restrict__ partial) {
    __shared__ int ln[NPATCH];
    __shared__ int ly[NPATCH];
    __shared__ int lx[NPATCH];
    __shared__ unsigned long long wm[4];
    __shared__ float sv[5][520];

    const int tid = threadIdx.x;
    const int lane = tid & 63;
    const int wid  = tid >> 6;
    const int tx0 = blockIdx.x * TW;
    const int ty0 = blockIdx.y * TH;
    const int chan = blockIdx.z;

    const int x0 = tx0 + lane * 4;
    const int y  = ty0 + wid;
    const int q = (y*WW + x0) >> 2;
    const int pq = chan*(HW_ >> 2) + q;

    const fx4* __restrict__ orig4 = (const fx4*)orig;
    fx4* __restrict__ out4 = (fx4*)out;

    const fx4 mq = ((const fx4*)mask)[q];
    fx4 v = __builtin_nontemporal_load(&orig4[pq]);

    if (tid < NPATCH) {
        const int yn = pos_y[tid], xn = pos_x[tid];
        const bool cov = (yn < ty0 + TH) && (yn + PSZ > ty0) &&
                         (xn < tx0 + TW) && (xn + PSZ > tx0);
        unsigned long long b = __ballot(cov);
        if (lane == 0) wm[wid] = b;
        BARLDS();
        if (cov) {
            int pos = __popcll(b & ((1ull << lane) - 1ull));
            for (int w = 0; w < wid; ++w) pos += __popcll(wm[w]);
            ln[pos] = tid; ly[pos] = yn; lx[pos] = xn;
        }
    } else {
        BARLDS();
    }
    BARLDS();
    const int cnt = __popcll(wm[0]) + __popcll(wm[1]) + __popcll(wm[2]) + __popcll(wm[3]);

    const float nhx = 1.f-mq.x, nhy = 1.f-mq.y, nhz = 1.f-mq.z, nhw = 1.f-mq.w;
    const float a_cnt = nhx+nhy+nhz+nhw;
    const float s1o = v.x*nhx+v.y*nhy+v.z*nhz+v.w*nhw;
    const float s2o = v.x*v.x*nhx+v.y*v.y*nhy+v.z*v.z*nhz+v.w*v.w*nhw;

    for (int k = 0; k < cnt; ++k) {
        const int dy = y - ly[k];
        if ((unsigned)dy >= (unsigned)PSZ) continue;
        const int dx0 = x0 - lx[k];
        if (dx0 <= -4 || dx0 >= PSZ) continue;
        const int nn = ln[k];
        const int rowb = dy << 7;
        const float* __restrict__ fmp = fm + nn*(PSZ*PSZ) + rowb;
        const float* __restrict__ pp  = patches + (nn*3 + chan)*(PSZ*PSZ) + rowb;
        if ((unsigned)dx0 <= (unsigned)(PSZ-4)) {
            const fx4u f4 = *(const fx4u*)(fmp + dx0);
            const fx4u p4 = *(const fx4u*)(pp + dx0);
            v.x += f4.x * (p4.x - v.x);
            v.y += f4.y * (p4.y - v.y);
            v.z += f4.z * (p4.z - v.z);
            v.w += f4.w * (p4.w - v.w);
        } else {
            #define BLEND(J, MX) { \
                const int dx = dx0 + J; \
                if ((unsigned)dx < (unsigned)PSZ) { \
                    const float f = fmp[dx]; \
                    v.MX += f * (pp[dx] - v.MX); \
                } }
            BLEND(0, x) BLEND(1, y) BLEND(2, z) BLEND(3, w)
            #undef BLEND
        }
    }

    out4[pq] = v;

    const float s1f = v.x*nhx+v.y*nhy+v.z*nhz+v.w*nhw;
    const float s2f = v.x*v.x*nhx+v.y*v.y*nhy+v.z*v.z*nhz+v.w*v.w*nhw;

    sv[0][tid] = s1o; sv[1][tid] = s2o; sv[2][tid] = s1f; sv[3][tid] = s2f; sv[4][tid] = a_cnt;
    BARLDS();
    if (wid < 5 && !(wid == 4 && chan != 0)) {
        const float* p = sv[wid];
        float t = p[lane] + p[lane+64] + p[lane+128] + p[lane+192]
                + p[lane+256] + p[lane+320] + p[lane+384] + p[lane+448];
        t += __shfl_down(t, 32); t += __shfl_down(t, 16);
        t += __shfl_down(t, 8);  t += __shfl_down(t, 4);
        t += __shfl_down(t, 2);  t += __shfl_down(t, 1);
        if (lane == 0) {
            const int bid = blockIdx.y * NBX + blockIdx.x;
            const int stat = (wid == 4) ? 0 : (1 + 3*wid + chan);
            partial[stat*NB + bid] = t;
        }
    }
}

// ---------------- finalize: 13 waves, one per statistic ----------------
__global__ __launch_bounds__(832) void finalize_kernel(
        const float* __restrict__ partial, float* __restrict__ coef) {
    __shared__ double tot[13];
    const int w = threadIdx.x >> 6;
    const int lane = threadIdx.x & 63;
    const float* p = partial + w*NB;
    double s0 = 0.0, s1 = 0.0;
    int b = lane;
    for (; b + 64 < NB; b += 128) { s0 += (double)p[b]; s1 += (double)p[b+64]; }
    if (b < NB) s0 += (double)p[b];
    double t = s0 + s1;
    t += __shfl_down(t, 32); t += __shfl_down(t, 16);
    t += __shfl_down(t, 8);  t += __shfl_down(t, 4);
    t += __shfl_down(t, 2);  t += __shfl_down(t, 1);
    if (lane == 0) tot[w] = t;
    __syncthreads();
    if (threadIdx.x == 0) {
        const double cnt = tot[0];
        for (int c = 0; c < 3; ++c) {
            double om = tot[1+c]/cnt;
            double ov = tot[4+c]/cnt - om*om;
            double os = sqrt(ov > 0.0 ? ov : 0.0);
            double fmn = tot[7+c]/cnt;
            double fv = tot[10+c]/cnt - fmn*fmn;
            double fs = sqrt(fv > 0.0 ? fv : 0.0);
            coef[c]   = (float)(os/(fs + 1e-8));
            coef[3+c] = (float)fmn;
            coef[6+c] = (float)om;
        }
    }
}

// ---------------- correct: hb-byte driven, one quad per thread ----------------
__global__ __launch_bounds__(256) void correct_kernel(
        float* __restrict__ out, const uchar* __restrict__ hbb,
        const float* __restrict__ coef) {
    const int q = blockIdx.x * 256 + threadIdx.x;
    if (q >= (HW_ >> 2)) return;
    const unsigned bits = hbb[q];
    if (!bits) return;
    const float r0 = coef[0], r1 = coef[1], r2 = coef[2];
    const float f0 = coef[3], f1 = coef[4], f2 = coef[5];
    const float o0 = coef[6], o1 = coef[7], o2 = coef[8];
    fx4* __restrict__ out4 = (fx4*)out;
    fx4 v0 = out4[q];
    fx4 v1 = out4[(HW_>>2)+q];
    fx4 v2 = out4[((2*HW_)>>2)+q];
    if (bits & 1u) { v0.x=(v0.x-f0)*r0+o0; v1.x=(v1.x-f1)*r1+o1; v2.x=(v2.x-f2)*r2+o2; }
    if (bits & 2u) { v0.y=(v0.y-f0)*r0+o0; v1.y=(v1.y-f1)*r1+o1; v2.y=(v2.y-f2)*r2+o2; }
    if (bits & 4u) { v0.z=(v0.z-f0)*r0+o0; v1.z=(v1.z-f1)*r1+o1; v2.z=(v2.z-f2)*r2+o2; }
    if (bits & 8u) { v0.w=(v0.w-f0)*r0+o0; v1.w=(v1.w-f1)*r1+o1; v2.w=(v2.w-f2)*r2+o2; }
    out4[q] = v0;
    out4[(HW_>>2)+q] = v1;
    out4[((2*HW_)>>2)+q] = v2;
}

// ---------------- fallback correct (mask-based) ----------------
__global__ __launch_bounds__(256) void correct_full_kernel(
        float* __restrict__ out, const float* __restrict__ mask,
        const float* __restrict__ coef) {
    const int q = blockIdx.x * 256 + threadIdx.x;
    if (q >= (HW_ >> 2)) return;
    const fx4 m = ((const fx4*)mask)[q];
    if (m.x == 0.f && m.y == 0.f && m.z == 0.f && m.w == 0.f) return;
    const float r0 = coef[0], r1 = coef[1], r2 = coef[2];
    const float f0 = coef[3], f1 = coef[4], f2 = coef[5];
    const float o0 = coef[6], o1 = coef[7], o2 = coef[8];
    fx4* __restrict__ out4 = (fx4*)out;
    fx4 v0 = out4[q];
    fx4 v1 = out4[(HW_>>2)+q];
    fx4 v2 = out4[((2*HW_)>>2)+q];
    if (m.x != 0.f) { v0.x=(v0.x-f0)*r0+o0; v1.x=(v1.x-f1)*r1+o1; v2.x=(v2.x-f2)*r2+o2; }
    if (m.y != 0.f) { v0.y=(v0.y-f0)*r0+o0; v1.y=(v1.y-f1)*r1+o1; v2.y=(v2.y-f2)*r2+o2; }
    if (m.z != 0.f) { v0.z=(v0.z-f0)*r0+o0; v1.z=(v1.z-f1)*r1+o1; v2.z=(v2.z-f2)*r2+o2; }
    if (m.w != 0.f) { v0.w=(v0.w-f0)*r0+o0; v1.w=(v1.w-f1)*r1+o1; v2.w=(v2.w-f2)*r2+o2; }
    out4[q] = v0;
    out4[(HW_>>2)+q] = v1;
    out4[((2*HW_)>>2)+q] = v2;
}

extern "C" void kernel_launch(void* const* d_in, const int* in_sizes, int n_in,
                              void* d_out, int out_size, void* d_ws, size_t ws_size,
                              hipStream_t stream) {
    const float* orig    = (const float*)d_in[0];
    const float* patches = (const float*)d_in[1];
    const float* mask    = (const float*)d_in[2];
    const int*   pos_y   = (const int*)d_in[3];
    const int*   pos_x   = (const int*)d_in[4];
    float* out = (float*)d_out;

    float*        fm      = (float*)d_ws;
    float*        coef    = (float*)((char*)d_ws + COEF_OFF);
    float*        partial = (float*)((char*)d_ws + PART_OFF);
    uchar*        hbb     = (uchar*)((char*)d_ws + HBB_OFF);
    unsigned int* tlist   = (unsigned int*)((char*)d_ws + TLIST_OFF);

    const bool fast = (ws_size >= WS_NEED);

    dim3 fg(NPATCH, 4);
    dim3 g(NBX, NBY, 3);
    if (fast) {
        hbbtl_kernel<<<NB, 256, 0, stream>>>(mask, pos_y, pos_x, hbb, tlist);
        feather_kernel<<<fg, 256, 0, stream>>>(mask, hbb, pos_y, pos_x, fm);
        compose_kernel<<<g, 512, 0, stream>>>(orig, patches, fm, out, partial, hbb, tlist);
        finalize_kernel<<<1, 832, 0, stream>>>(partial, coef);
        correct_kernel<<<((HW_ >> 2) + 255)/256, 256, 0, stream>>>(out, hbb, coef);
    } else {
        feather_kernel<<<fg, 256, 0, stream>>>(mask, nullptr, pos_y, pos_x, fm);
        compose_fb_kernel<<<g, 512, 0, stream>>>(orig, patches, mask, pos_y, pos_x, fm,
                                                 out, partial);
        finalize_kernel<<<1, 832, 0, stream>>>(partial, coef);
        correct_full_kernel<<<((HW_ >> 2) + 255)/256, 256, 0, stream>>>(out, mask, coef);
    }
}

// Round 17
// 121.663 us; speedup vs baseline: 1.1722x; 1.0327x over previous
//
#include <hip/hip_runtime.h>

#define HH 2160
#define WW 3840
#define NPATCH 256
#define PSZ 128
#define HW_ (HH*WW)
#define FMSZ (NPATCH*PSZ*PSZ)

#define TW 256
#define TH 8
#define NBX (WW/TW)     // 15
#define NBY (HH/TH)     // 270
#define NB  (NBX*NBY)   // 4050
#define TSTRIDE (NPATCH+1)

typedef float fx4 __attribute__((ext_vector_type(4)));
typedef float fx4u __attribute__((ext_vector_type(4), aligned(4)));
typedef unsigned char uchar;

// ws layout: fm | tot(13 dbl) | done | coef | partial[13][NB] | hbb | tlist
#define TOT_OFF   ((size_t)FMSZ*4)
#define DONE_OFF  (TOT_OFF + 104)
#define COEF_OFF  (TOT_OFF + 128)
#define PART_OFF  (TOT_OFF + 192)
#define HBB_OFF   ((PART_OFF + (size_t)13*NB*4 + 63)/64*64)
#define TLIST_OFF ((HBB_OFF + (size_t)(HW_/4) + 63)/64*64)
#define WS_NEED   (TLIST_OFF + (size_t)NB*TSTRIDE*4)

// barrier that does NOT drain vmcnt
#define BARLDS() do { \
    asm volatile("s_waitcnt lgkmcnt(0)" ::: "memory"); \
    __builtin_amdgcn_s_barrier(); \
    asm volatile("" ::: "memory"); \
} while (0)

// ---------------- fused: hole-byte map + per-tile ordered patch list + tot/done zero ----------------
__global__ __launch_bounds__(256) void hbbtl_kernel(
        const float* __restrict__ mask, const int* __restrict__ pos_y,
        const int* __restrict__ pos_x, uchar* __restrict__ hbb,
        unsigned int* __restrict__ tlist, double* __restrict__ tot,
        unsigned int* __restrict__ done) {
    __shared__ unsigned long long wm[4];
    const int tile = blockIdx.x;
    const int tx0 = (tile % NBX) * TW;
    const int ty0 = (tile / NBX) * TH;
    const int tid = threadIdx.x;
    const int lane = tid & 63;
    const int wid  = tid >> 6;

    if (tile == 0) {
        if (tid < 13) tot[tid] = 0.0;
        if (tid == 13) *done = 0u;
    }

    // hbb for this tile's 512 quads (2 per thread)
    #pragma unroll
    for (int h = 0; h < 2; ++h) {
        const int l = tid + h*256;
        const int row = l >> 6, col = l & 63;
        const int q = (ty0+row)*(WW >> 2) + (tx0 >> 2) + col;
        const fx4 m = ((const fx4*)mask)[q];
        hbb[q] = (uchar)((unsigned)(m.x!=0.f) | ((unsigned)(m.y!=0.f)<<1)
                       | ((unsigned)(m.z!=0.f)<<2) | ((unsigned)(m.w!=0.f)<<3));
    }

    // ordered (ascending n) patch list for this tile
    const int yn = pos_y[tid], xn = pos_x[tid];
    const bool cov = (yn < ty0 + TH) && (yn + PSZ > ty0) &&
                     (xn < tx0 + TW) && (xn + PSZ > tx0);
    unsigned long long b = __ballot(cov);
    if (lane == 0) wm[wid] = b;
    __syncthreads();
    unsigned int* tl = tlist + (size_t)tile * TSTRIDE;
    if (cov) {
        int pos = __popcll(b & ((1ull << lane) - 1ull));
        for (int w = 0; w < wid; ++w) pos += __popcll(wm[w]);
        tl[1 + pos] = ((unsigned)tid << 24) | ((unsigned)yn << 12) | (unsigned)xn;
    }
    if (tid == 0)
        tl[0] = (unsigned)(__popcll(wm[0]) + __popcll(wm[1]) + __popcll(wm[2]) + __popcll(wm[3]));
}

// ---------------- feather: separable 9-tap gaussian, zero-padded per patch ----------------
__global__ __launch_bounds__(256) void feather_kernel(
        const float* __restrict__ mask, const uchar* __restrict__ hbb,
        const int* __restrict__ pos_y, const int* __restrict__ pos_x,
        float* __restrict__ fm) {
    __shared__ float sm[40*PSZ];
    __shared__ float tp[40*PSZ];
    const int n = blockIdx.x;
    const int r0 = blockIdx.y * 32;
    const int y0 = pos_y[n], x0 = pos_x[n];
    float g[9]; float s = 0.f;
    #pragma unroll
    for (int k = 0; k < 9; ++k) { float xx = (k-4)*0.75f; g[k] = expf(-0.5f*xx*xx); s += g[k]; }
    const float inv = 1.f/s;
    #pragma unroll
    for (int k = 0; k < 9; ++k) g[k] *= inv;

    for (int idx = threadIdx.x; idx < 40*PSZ; idx += 256) {
        int l = idx >> 7, j = idx & 127;
        int r = r0 + l - 4;
        float mv = 0.f;
        if ((unsigned)r < (unsigned)PSZ) {
            const int pix = (y0+r)*WW + (x0+j);
            if (hbb) mv = (float)((hbb[pix >> 2] >> (pix & 3)) & 1u);
            else     mv = mask[pix];
        }
        sm[idx] = mv;
    }
    __syncthreads();
    for (int idx = threadIdx.x; idx < 40*PSZ; idx += 256) {
        int l = idx >> 7, j = idx & 127;
        float a = 0.f;
        #pragma unroll
        for (int d = -4; d <= 4; ++d) {
            int jj = j + d;
            if (jj >= 0 && jj < PSZ) a += sm[(l<<7)+jj]*g[d+4];
        }
        tp[idx] = a;
    }
    __syncthreads();
    float* o = fm + n*(PSZ*PSZ) + r0*PSZ;
    for (int idx = threadIdx.x; idx < 32*PSZ; idx += 256) {
        int i = idx >> 7, j = idx & 127;
        float a = 0.f;
        #pragma unroll
        for (int d = 0; d < 9; ++d) a += tp[((i+d)<<7)+j]*g[d];
        o[idx] = a;
    }
}

// ---------------- compose (primary): tlist-driven, no startup barriers (R16 verbatim) ----------------
__global__ __launch_bounds__(512) void compose_kernel(
        const float* __restrict__ orig, const float* __restrict__ patches,
        const float* __restrict__ fm, float* __restrict__ out,
        float* __restrict__ partial, const uchar* __restrict__ hbb,
        const unsigned int* __restrict__ tlist) {
    __shared__ float sv[5][520];

    const int tid = threadIdx.x;
    const int lane = tid & 63;
    const int wid  = tid >> 6;              // 0..7 = row within tile
    const int tx0 = blockIdx.x * TW;
    const int ty0 = blockIdx.y * TH;
    const int chan = blockIdx.z;

    const int x0 = tx0 + lane * 4;          // this thread's pixel quad
    const int y  = ty0 + wid;               // this thread's row
    const int q = (y*WW + x0) >> 2;
    const int pq = chan*(HW_ >> 2) + q;

    const fx4* __restrict__ orig4 = (const fx4*)orig;
    fx4* __restrict__ out4 = (fx4*)out;

    // per-thread vector loads issue immediately
    const uchar hbv = hbb[q];
    fx4 v = __builtin_nontemporal_load(&orig4[pq]);

    // block-uniform tile list -> scalar loads
    const unsigned int* __restrict__ tl =
        tlist + (size_t)(blockIdx.y * NBX + blockIdx.x) * TSTRIDE;
    const int cnt = (int)tl[0];

    const float nhx = (hbv & 1u) ? 0.f : 1.f;
    const float nhy = (hbv & 2u) ? 0.f : 1.f;
    const float nhz = (hbv & 4u) ? 0.f : 1.f;
    const float nhw = (hbv & 8u) ? 0.f : 1.f;

    const float a_cnt = nhx+nhy+nhz+nhw;
    const float s1o = v.x*nhx+v.y*nhy+v.z*nhz+v.w*nhw;
    const float s2o = v.x*v.x*nhx+v.y*v.y*nhy+v.z*v.z*nhz+v.w*v.w*nhw;

    for (int k = 0; k < cnt; ++k) {
        const unsigned e = tl[1 + k];
        const int xk = (int)(e & 0xFFFu);
        const int yk = (int)((e >> 12) & 0xFFFu);
        const int nn = (int)(e >> 24);
        const int dy = y - yk;
        if ((unsigned)dy >= (unsigned)PSZ) continue;
        const int dx0 = x0 - xk;
        if (dx0 <= -4 || dx0 >= PSZ) continue;
        const int rowb = dy << 7;
        const float* __restrict__ fmp = fm + nn*(PSZ*PSZ) + rowb;
        const float* __restrict__ pp  = patches + (nn*3 + chan)*(PSZ*PSZ) + rowb;
        if ((unsigned)dx0 <= (unsigned)(PSZ-4)) {
            const fx4u f4 = *(const fx4u*)(fmp + dx0);
            const fx4u p4 = *(const fx4u*)(pp + dx0);
            v.x += f4.x * (p4.x - v.x);
            v.y += f4.y * (p4.y - v.y);
            v.z += f4.z * (p4.z - v.z);
            v.w += f4.w * (p4.w - v.w);
        } else {
            #define BLEND(J, MX) { \
                const int dx = dx0 + J; \
                if ((unsigned)dx < (unsigned)PSZ) { \
                    const float f = fmp[dx]; \
                    v.MX += f * (pp[dx] - v.MX); \
                } }
            BLEND(0, x) BLEND(1, y) BLEND(2, z) BLEND(3, w)
            #undef BLEND
        }
    }

    out4[pq] = v;

    const float s1f = v.x*nhx+v.y*nhy+v.z*nhz+v.w*nhw;
    const float s2f = v.x*v.x*nhx+v.y*v.y*nhy+v.z*v.z*nhz+v.w*v.w*nhw;

    // --- tail: LDS transpose, 5 waves reduce 512 values each ---
    sv[0][tid] = s1o; sv[1][tid] = s2o; sv[2][tid] = s1f; sv[3][tid] = s2f; sv[4][tid] = a_cnt;
    BARLDS();
    if (wid < 5 && !(wid == 4 && chan != 0)) {
        const float* p = sv[wid];
        float t = p[lane] + p[lane+64] + p[lane+128] + p[lane+192]
                + p[lane+256] + p[lane+320] + p[lane+384] + p[lane+448];
        t += __shfl_down(t, 32); t += __shfl_down(t, 16);
        t += __shfl_down(t, 8);  t += __shfl_down(t, 4);
        t += __shfl_down(t, 2);  t += __shfl_down(t, 1);
        if (lane == 0) {
            const int bid = blockIdx.y * NBX + blockIdx.x;
            const int stat = (wid == 4) ? 0 : (1 + 3*wid + chan);
            partial[stat*NB + bid] = t;
        }
    }
}

// ---------------- compose fallback (ws too small): in-block ballot, mask-based ----------------
__global__ __launch_bounds__(512) void compose_fb_kernel(
        const float* __restrict__ orig, const float* __restrict__ patches,
        const float* __restrict__ mask, const int* __restrict__ pos_y,
        const int* __restrict__ pos_x, const float* __restrict__ fm,
        float* __restrict__ out, float* __restrict__ partial) {
    __shared__ int ln[NPATCH];
    __shared__ int ly[NPATCH];
    __shared__ int lx[NPATCH];
    __shared__ unsigned long long wm[4];
    __shared__ float sv[5][520];

    const int tid = threadIdx.x;
    const int lane = tid & 63;
    const int wid  = tid >> 6;
    const int tx0 = blockIdx.x * TW;
    const int ty0 = blockIdx.y * TH;
    const int chan = blockIdx.z;

    const int x0 = tx0 + lane * 4;
    const int y  = ty0 + wid;
    const int q = (y*WW + x0) >> 2;
    const int pq = chan*(HW_ >> 2) + q;

    const fx4* __restrict__ orig4 = (const fx4*)orig;
    fx4* __restrict__ out4 = (fx4*)out;

    const fx4 mq = ((const fx4*)mask)[q];
    fx4 v = __builtin_nontemporal_load(&orig4[pq]);

    if (tid < NPATCH) {
        const int yn = pos_y[tid], xn = pos_x[tid];
        const bool cov = (yn < ty0 + TH) && (yn + PSZ > ty0) &&
                         (xn < tx0 + TW) && (xn + PSZ > tx0);
        unsigned long long b = __ballot(cov);
        if (lane == 0) wm[wid] = b;
        BARLDS();
        if (cov) {
            int pos = __popcll(b & ((1ull << lane) - 1ull));
            for (int w = 0; w < wid; ++w) pos += __popcll(wm[w]);
            ln[pos] = tid; ly[pos] = yn; lx[pos] = xn;
        }
    } else {
        BARLDS();
    }
    BARLDS();
    const int cnt = __popcll(wm[0]) + __popcll(wm[1]) + __popcll(wm[2]) + __popcll(wm[3]);

    const float nhx = 1.f-mq.x, nhy = 1.f-mq.y, nhz = 1.f-mq.z, nhw = 1.f-mq.w;
    const float a_cnt = nhx+nhy+nhz+nhw;
    const float s1o = v.x*nhx+v.y*nhy+v.z*nhz+v.w*nhw;
    const float s2o = v.x*v.x*nhx+v.y*v.y*nhy+v.z*v.z*nhz+v.w*v.w*nhw;

    for (int k = 0; k < cnt; ++k) {
        const int dy = y - ly[k];
        if ((unsigned)dy >= (unsigned)PSZ) continue;
        const int dx0 = x0 - lx[k];
        if (dx0 <= -4 || dx0 >= PSZ) continue;
        const int nn = ln[k];
        const int rowb = dy << 7;
        const float* __restrict__ fmp = fm + nn*(PSZ*PSZ) + rowb;
        const float* __restrict__ pp  = patches + (nn*3 + chan)*(PSZ*PSZ) + rowb;
        if ((unsigned)dx0 <= (unsigned)(PSZ-4)) {
            const fx4u f4 = *(const fx4u*)(fmp + dx0);
            const fx4u p4 = *(const fx4u*)(pp + dx0);
            v.x += f4.x * (p4.x - v.x);
            v.y += f4.y * (p4.y - v.y);
            v.z += f4.z * (p4.z - v.z);
            v.w += f4.w * (p4.w - v.w);
        } else {
            #define BLEND(J, MX) { \
                const int dx = dx0 + J; \
                if ((unsigned)dx < (unsigned)PSZ) { \
                    const float f = fmp[dx]; \
                    v.MX += f * (pp[dx] - v.MX); \
                } }
            BLEND(0, x) BLEND(1, y) BLEND(2, z) BLEND(3, w)
            #undef BLEND
        }
    }

    out4[pq] = v;

    const float s1f = v.x*nhx+v.y*nhy+v.z*nhz+v.w*nhw;
    const float s2f = v.x*v.x*nhx+v.y*v.y*nhy+v.z*v.z*nhz+v.w*v.w*nhw;

    sv[0][tid] = s1o; sv[1][tid] = s2o; sv[2][tid] = s1f; sv[3][tid] = s2f; sv[4][tid] = a_cnt;
    BARLDS();
    if (wid < 5 && !(wid == 4 && chan != 0)) {
        const float* p = sv[wid];
        float t = p[lane] + p[lane+64] + p[lane+128] + p[lane+192]
                + p[lane+256] + p[lane+320] + p[lane+384] + p[lane+448];
        t += __shfl_down(t, 32); t += __shfl_down(t, 16);
        t += __shfl_down(t, 8);  t += __shfl_down(t, 4);
        t += __shfl_down(t, 2);  t += __shfl_down(t, 1);
        if (lane == 0) {
            const int bid = blockIdx.y * NBX + blockIdx.x;
            const int stat = (wid == 4) ? 0 : (1 + 3*wid + chan);
            partial[stat*NB + bid] = t;
        }
    }
}

// ---------------- finalize: 13 blocks, one statistic each; last block emits coef ----------------
__global__ __launch_bounds__(256) void finalize_kernel(
        const float* __restrict__ partial, double* __restrict__ tot,
        unsigned int* __restrict__ done, float* __restrict__ coef) {
    __shared__ double red[4];
    __shared__ bool last;
    const int s = blockIdx.x;               // statistic 0..12
    const int tid = threadIdx.x;
    const int lane = tid & 63;
    const int w = tid >> 6;
    const float* __restrict__ p = partial + (size_t)s*NB;
    double acc = 0.0;
    for (int i = tid; i < NB; i += 256) acc += (double)p[i];
    acc += __shfl_down(acc, 32); acc += __shfl_down(acc, 16);
    acc += __shfl_down(acc, 8);  acc += __shfl_down(acc, 4);
    acc += __shfl_down(acc, 2);  acc += __shfl_down(acc, 1);
    if (lane == 0) red[w] = acc;
    __syncthreads();
    if (tid == 0) {
        atomicAdd(&tot[s], red[0] + red[1] + red[2] + red[3]);
        __threadfence();
        last = (atomicAdd(done, 1u) == 12u);
    }
    __syncthreads();
    if (last && tid == 0) {
        const double cnt = tot[0];
        for (int c = 0; c < 3; ++c) {
            double om = tot[1+c]/cnt;
            double ov = tot[4+c]/cnt - om*om;
            double os = sqrt(ov > 0.0 ? ov : 0.0);
            double fmn = tot[7+c]/cnt;
            double fv = tot[10+c]/cnt - fmn*fmn;
            double fs = sqrt(fv > 0.0 ? fv : 0.0);
            coef[c]   = (float)(os/(fs + 1e-8));
            coef[3+c] = (float)fmn;
            coef[6+c] = (float)om;
        }
    }
}

// ---------------- correct: hb-byte driven, one quad per thread ----------------
__global__ __launch_bounds__(256) void correct_kernel(
        float* __restrict__ out, const uchar* __restrict__ hbb,
        const float* __restrict__ coef) {
    const int q = blockIdx.x * 256 + threadIdx.x;
    if (q >= (HW_ >> 2)) return;
    const unsigned bits = hbb[q];
    if (!bits) return;
    const float r0 = coef[0], r1 = coef[1], r2 = coef[2];
    const float f0 = coef[3], f1 = coef[4], f2 = coef[5];
    const float o0 = coef[6], o1 = coef[7], o2 = coef[8];
    fx4* __restrict__ out4 = (fx4*)out;
    fx4 v0 = out4[q];
    fx4 v1 = out4[(HW_>>2)+q];
    fx4 v2 = out4[((2*HW_)>>2)+q];
    if (bits & 1u) { v0.x=(v0.x-f0)*r0+o0; v1.x=(v1.x-f1)*r1+o1; v2.x=(v2.x-f2)*r2+o2; }
    if (bits & 2u) { v0.y=(v0.y-f0)*r0+o0; v1.y=(v1.y-f1)*r1+o1; v2.y=(v2.y-f2)*r2+o2; }
    if (bits & 4u) { v0.z=(v0.z-f0)*r0+o0; v1.z=(v1.z-f1)*r1+o1; v2.z=(v2.z-f2)*r2+o2; }
    if (bits & 8u) { v0.w=(v0.w-f0)*r0+o0; v1.w=(v1.w-f1)*r1+o1; v2.w=(v2.w-f2)*r2+o2; }
    out4[q] = v0;
    out4[(HW_>>2)+q] = v1;
    out4[((2*HW_)>>2)+q] = v2;
}

// ---------------- fallback finalize (single block) + correct (mask-based) ----------------
__global__ __launch_bounds__(832) void finalize_fb_kernel(
        const float* __restrict__ partial, float* __restrict__ coef) {
    __shared__ double tot[13];
    const int w = threadIdx.x >> 6;
    const int lane = threadIdx.x & 63;
    const float* p = partial + w*NB;
    double s0 = 0.0, s1 = 0.0;
    int b = lane;
    for (; b + 64 < NB; b += 128) { s0 += (double)p[b]; s1 += (double)p[b+64]; }
    if (b < NB) s0 += (double)p[b];
    double t = s0 + s1;
    t += __shfl_down(t, 32); t += __shfl_down(t, 16);
    t += __shfl_down(t, 8);  t += __shfl_down(t, 4);
    t += __shfl_down(t, 2);  t += __shfl_down(t, 1);
    if (lane == 0) tot[w] = t;
    __syncthreads();
    if (threadIdx.x == 0) {
        const double cnt = tot[0];
        for (int c = 0; c < 3; ++c) {
            double om = tot[1+c]/cnt;
            double ov = tot[4+c]/cnt - om*om;
            double os = sqrt(ov > 0.0 ? ov : 0.0);
            double fmn = tot[7+c]/cnt;
            double fv = tot[10+c]/cnt - fmn*fmn;
            double fs = sqrt(fv > 0.0 ? fv : 0.0);
            coef[c]   = (float)(os/(fs + 1e-8));
            coef[3+c] = (float)fmn;
            coef[6+c] = (float)om;
        }
    }
}

__global__ __launch_bounds__(256) void correct_full_kernel(
        float* __restrict__ out, const float* __restrict__ mask,
        const float* __restrict__ coef) {
    const int q = blockIdx.x * 256 + threadIdx.x;
    if (q >= (HW_ >> 2)) return;
    const fx4 m = ((const fx4*)mask)[q];
    if (m.x == 0.f && m.y == 0.f && m.z == 0.f && m.w == 0.f) return;
    const float r0 = coef[0], r1 = coef[1], r2 = coef[2];
    const float f0 = coef[3], f1 = coef[4], f2 = coef[5];
    const float o0 = coef[6], o1 = coef[7], o2 = coef[8];
    fx4* __restrict__ out4 = (fx4*)out;
    fx4 v0 = out4[q];
    fx4 v1 = out4[(HW_>>2)+q];
    fx4 v2 = out4[((2*HW_)>>2)+q];
    if (m.x != 0.f) { v0.x=(v0.x-f0)*r0+o0; v1.x=(v1.x-f1)*r1+o1; v2.x=(v2.x-f2)*r2+o2; }
    if (m.y != 0.f) { v0.y=(v0.y-f0)*r0+o0; v1.y=(v1.y-f1)*r1+o1; v2.y=(v2.y-f2)*r2+o2; }
    if (m.z != 0.f) { v0.z=(v0.z-f0)*r0+o0; v1.z=(v1.z-f1)*r1+o1; v2.z=(v2.z-f2)*r2+o2; }
    if (m.w != 0.f) { v0.w=(v0.w-f0)*r0+o0; v1.w=(v1.w-f1)*r1+o1; v2.w=(v2.w-f2)*r2+o2; }
    out4[q] = v0;
    out4[(HW_>>2)+q] = v1;
    out4[((2*HW_)>>2)+q] = v2;
}

extern "C" void kernel_launch(void* const* d_in, const int* in_sizes, int n_in,
                              void* d_out, int out_size, void* d_ws, size_t ws_size,
                              hipStream_t stream) {
    const float* orig    = (const float*)d_in[0];
    const float* patches = (const float*)d_in[1];
    const float* mask    = (const float*)d_in[2];
    const int*   pos_y   = (const int*)d_in[3];
    const int*   pos_x   = (const int*)d_in[4];
    float* out = (float*)d_out;

    float*        fm      = (float*)d_ws;
    double*       tot     = (double*)((char*)d_ws + TOT_OFF);
    unsigned int* done    = (unsigned int*)((char*)d_ws + DONE_OFF);
    float*        coef    = (float*)((char*)d_ws + COEF_OFF);
    float*        partial = (float*)((char*)d_ws + PART_OFF);
    uchar*        hbb     = (uchar*)((char*)d_ws + HBB_OFF);
    unsigned int* tlist   = (unsigned int*)((char*)d_ws + TLIST_OFF);

    const bool fast = (ws_size >= WS_NEED);

    dim3 fg(NPATCH, 4);
    dim3 g(NBX, NBY, 3);
    if (fast) {
        hbbtl_kernel<<<NB, 256, 0, stream>>>(mask, pos_y, pos_x, hbb, tlist, tot, done);
        feather_kernel<<<fg, 256, 0, stream>>>(mask, hbb, pos_y, pos_x, fm);
        compose_kernel<<<g, 512, 0, stream>>>(orig, patches, fm, out, partial, hbb, tlist);
        finalize_kernel<<<13, 256, 0, stream>>>(partial, tot, done, coef);
        correct_kernel<<<((HW_ >> 2) + 255)/256, 256, 0, stream>>>(out, hbb, coef);
    } else {
        feather_kernel<<<fg, 256, 0, stream>>>(mask, nullptr, pos_y, pos_x, fm);
        compose_fb_kernel<<<g, 512, 0, stream>>>(orig, patches, mask, pos_y, pos_x, fm,
                                                 out, partial);
        finalize_fb_kernel<<<1, 832, 0, stream>>>(partial, coef);
        correct_full_kernel<<<((HW_ >> 2) + 255)/256, 256, 0, stream>>>(out, mask, coef);
    }
}